// Round 1
// baseline (485.652 us; speedup 1.0000x reference)
//
#include <hip/hip_runtime.h>
#include <math.h>

#define ALPHA 0.1f
#define EPS 1e-7f

constexpr int D = 65;        // 1 time-like + 64 space dims
constexpr int A = 16;        // anchors
constexpr int ROWS = 256;    // rows per block = threads per block

// ---------------------------------------------------------------------------
// Prep: project anchors (recompute t = sqrt(1+|s|^2)), write to ws:
//   ws[0 .. A*D)      : transposed  aT[j*A + a]  (for wave-uniform s_loads)
//   ws[A*D .. 2*A*D)  : row-major   aRM[a*D + j] (for divergent LDS access)
// ---------------------------------------------------------------------------
__global__ void prep_anchors(const float* __restrict__ anchors,
                             float* __restrict__ ws) {
    __shared__ float s_a[A * D];
    int tid = threadIdx.x;
    for (int i = tid; i < A * D; i += blockDim.x) s_a[i] = anchors[i];
    __syncthreads();
    if (tid < A) {
        float s = 0.f;
        for (int j = 1; j < D; ++j) {
            float v = s_a[tid * D + j];
            s = fmaf(v, v, s);
        }
        s_a[tid * D] = sqrtf(1.f + s);
    }
    __syncthreads();
    for (int i = tid; i < A * D; i += blockDim.x) {
        int a = i / D, j = i % D;
        ws[j * A + a]  = s_a[i];   // transposed
        ws[A * D + i]  = s_a[i];   // row-major (projected)
    }
}

// ---------------------------------------------------------------------------
// Main: one thread per row.
// ---------------------------------------------------------------------------
__global__ __launch_bounds__(ROWS) void
homeo_kernel(const float* __restrict__ x,
             const float* __restrict__ aT,    // [D][A] transposed, projected
             const float* __restrict__ aRM,   // [A][D] row-major, projected
             float* __restrict__ out, int B) {
    __shared__ float xs[ROWS * D];   // 66560 B tile (input, then reused for output)
    __shared__ float anch[A * D];    // 4160 B projected anchors (divergent access)

    const int tid = threadIdx.x;
    const long rowStart = (long)blockIdx.x * ROWS;
    const int nRows = min(ROWS, B - (int)rowStart);
    const int nF4 = nRows * D / 4;   // 256 and 64 rows both divisible by 4

    // coalesced float4 staging of the tile (base = rowStart*260 B, 16B aligned)
    const float4* g4 = (const float4*)(x + rowStart * D);
    float4* s4 = (float4*)xs;
    for (int i = tid; i < nF4; i += ROWS) s4[i] = g4[i];
    for (int i = tid; i < A * D; i += ROWS) anch[i] = aRM[i];
    __syncthreads();

    if (tid < nRows) {
        // row into registers (bank = (tid + j) % 32 -> conflict-free rotation)
        float xr[D];
#pragma unroll
        for (int j = 0; j < D; ++j) xr[j] = xs[tid * D + j];

        // 16 Lorentz inner products; anchors via wave-uniform loads (-> SGPRs)
        float acc[A];
#pragma unroll
        for (int a = 0; a < A; ++a) acc[a] = -xr[0] * aT[a];   // j = 0 (time-like)
#pragma unroll
        for (int j = 1; j < D; ++j) {
            const float xj = xr[j];
#pragma unroll
            for (int a = 0; a < A; ++a)
                acc[a] = fmaf(xj, aT[j * A + a], acc[a]);
        }

        // argmin of acosh(max(-inner, 1+eps)) == argmin of max(-inner, 1+eps)
        const float onePlusEps = 1.0f + EPS;
        float bestZ = fmaxf(-acc[0], onePlusEps);
        float xy = acc[0];
        int bidx = 0;
#pragma unroll
        for (int a = 1; a < A; ++a) {
            float z = fmaxf(-acc[a], onePlusEps);
            if (z < bestZ) { bestZ = z; bidx = a; xy = acc[a]; }   // strict < : first-index ties
        }

        const float d = acoshf(bestZ);            // = safe_acosh(-xy)
        const float* na = anch + bidx * D;

        // uu = linner(u,u), u = na + xy*x
        float uu;
        {
            float u0 = fmaf(xy, xr[0], na[0]);
            uu = -u0 * u0;
#pragma unroll
            for (int j = 1; j < D; ++j) {
                float uj = fmaf(xy, xr[j], na[j]);
                uu = fmaf(uj, uj, uu);
            }
        }
        const float unorm = sqrtf(fmaxf(uu, EPS));
        const float c = ALPHA * d / unorm;        // v = c * u
        const float vv = c * c * uu;              // linner(v,v)
        const float vn = sqrtf(fmaxf(vv, EPS * EPS));
        const float sinhc = (vn > EPS) ? (sinhf(vn) / vn) : 1.0f;
        const float ch = coshf(vn);
        const float sc = sinhc * c;

        // out_j = cosh(vn)*x_j + sinhc*v_j ; v_j = c*(na_j + xy*x_j); write into LDS tile
#pragma unroll
        for (int j = 0; j < D; ++j) {
            float uj = fmaf(xy, xr[j], na[j]);
            xs[tid * D + j] = fmaf(ch, xr[j], sc * uj);
        }
    }
    __syncthreads();

    // coalesced float4 store
    float4* o4 = (float4*)(out + rowStart * D);
    for (int i = tid; i < nF4; i += ROWS) o4[i] = s4[i];
}

extern "C" void kernel_launch(void* const* d_in, const int* in_sizes, int n_in,
                              void* d_out, int out_size, void* d_ws, size_t ws_size,
                              hipStream_t stream) {
    const float* hyp = (const float*)d_in[0];
    const float* anchors = (const float*)d_in[1];
    float* out = (float*)d_out;
    float* ws = (float*)d_ws;

    const int B = in_sizes[0] / D;   // 1,000,000

    prep_anchors<<<1, 256, 0, stream>>>(anchors, ws);

    const int grid = (B + ROWS - 1) / ROWS;
    homeo_kernel<<<grid, ROWS, 0, stream>>>(hyp, ws, ws + A * D, out, B);
}

// Round 2
// 440.998 us; speedup vs baseline: 1.1013x; 1.1013x over previous
//
#include <hip/hip_runtime.h>
#include <math.h>
#include <stdint.h>

#define ALPHA 0.1f
#define EPS 1e-7f

constexpr int D = 65;                 // 1 time-like + 64 space dims
constexpr int A = 16;                 // anchors
constexpr int WPB = 4;                // waves per block
constexpr int TPB = WPB * 64;         // 256 threads
constexpr int RPW = 64;               // rows per wave-group
constexpr int WAVE_FLOATS = RPW * D;  // 4160 floats = 16640 B per wave region

// ---------------------------------------------------------------------------
// async global->LDS DMA helpers (gfx950: size 4 or 16). LDS dest is
// wave-uniform base + lane*size; global addr is per-lane.
// ---------------------------------------------------------------------------
__device__ __forceinline__ void async_cp16(const float* g, float* l) {
    __builtin_amdgcn_global_load_lds(
        (const __attribute__((address_space(1))) uint32_t*)(uintptr_t)g,
        (__attribute__((address_space(3))) uint32_t*)(uint32_t)(uintptr_t)l,
        16, 0, 0);
}
__device__ __forceinline__ void async_cp4(const float* g, float* l) {
    __builtin_amdgcn_global_load_lds(
        (const __attribute__((address_space(1))) uint32_t*)(uintptr_t)g,
        (__attribute__((address_space(3))) uint32_t*)(uint32_t)(uintptr_t)l,
        4, 0, 0);
}

// ---------------------------------------------------------------------------
// Prep: project anchors, write to ws:
//   ws[0 .. A*D)      : transposed  aT[j*A + a]  (wave-uniform s_loads)
//   ws[A*D .. 2*A*D)  : row-major   aRM[a*D + j] (staged to LDS for na)
// ---------------------------------------------------------------------------
__global__ void prep_anchors(const float* __restrict__ anchors,
                             float* __restrict__ ws) {
    __shared__ float s_a[A * D];
    int tid = threadIdx.x;
    for (int i = tid; i < A * D; i += blockDim.x) s_a[i] = anchors[i];
    __syncthreads();
    if (tid < A) {
        float s = 0.f;
        for (int j = 1; j < D; ++j) {
            float v = s_a[tid * D + j];
            s = fmaf(v, v, s);
        }
        s_a[tid * D] = sqrtf(1.f + s);
    }
    __syncthreads();
    for (int i = tid; i < A * D; i += blockDim.x) {
        int a = i / D, j = i % D;
        ws[j * A + a] = s_a[i];    // transposed
        ws[A * D + i] = s_a[i];    // row-major (projected)
    }
}

// ---------------------------------------------------------------------------
// Main: wave-group = 64 rows, private LDS region, no cross-wave sync after
// the one anchor barrier. One thread per row.
// ---------------------------------------------------------------------------
__global__ __launch_bounds__(TPB, 2) void
homeo_kernel(const float* __restrict__ x,
             const float* __restrict__ aT,    // [D][A] transposed, projected
             const float* __restrict__ aRM,   // [A][D] row-major, projected
             float* __restrict__ out, int B, int nWG) {
    __shared__ float xs[WPB * WAVE_FLOATS];  // 66560 B
    __shared__ float anch[A * D];            // 4160 B  -> 2 blocks/CU

    const int tid = threadIdx.x;
    const int wave = tid >> 6;
    const int lane = tid & 63;
    const int wg = blockIdx.x * WPB + wave;       // wave-group id (wave-uniform)
    const bool active = wg < nWG;

    float* lbase = xs + wave * WAVE_FLOATS;
    const long rowStart = (long)wg * RPW;
    const int nRows = active ? (int)min((long)RPW, (long)B - rowStart) : 0;

    // ---- issue async DMA for this wave's 16640 B tile (fire-and-forget) ----
    if (active && nRows == RPW) {
        const float* gbase = x + rowStart * D;
#pragma unroll
        for (int c = 0; c < 16; ++c)
            async_cp16(gbase + c * 256 + lane * 4, lbase + c * 256);
        async_cp4(gbase + 16 * 256 + lane, lbase + 16 * 256);   // 256 B tail
    } else if (active && lane < nRows) {
        // partial wave-group (unused at B=1e6): safe scalar staging
        for (int j = 0; j < D; ++j)
            lbase[lane * D + j] = x[(rowStart + lane) * D + j];
    }

    // ---- anchors -> LDS; barrier drains each wave's vmcnt (DMA complete) ----
    for (int i = tid; i < A * D; i += TPB) anch[i] = aRM[i];
    __syncthreads();

    if (active && lane < nRows) {
        // row into registers: bank = (lane + j) % 32, conflict-free rotation
        float xr[D];
#pragma unroll
        for (int j = 0; j < D; ++j) xr[j] = lbase[lane * D + j];

        // 16 Lorentz inner products; aT via wave-uniform loads (SGPR path)
        float acc[A];
#pragma unroll
        for (int a = 0; a < A; ++a) acc[a] = -xr[0] * aT[a];
#pragma unroll
        for (int j = 1; j < D; ++j) {
            const float xj = xr[j];
#pragma unroll
            for (int a = 0; a < A; ++a)
                acc[a] = fmaf(xj, aT[j * A + a], acc[a]);
        }

        // argmin of acosh(max(-inner,1+eps)); strict < = first-index ties
        const float onePlusEps = 1.0f + EPS;
        float bestZ = fmaxf(-acc[0], onePlusEps);
        float xy = acc[0];
        int bidx = 0;
#pragma unroll
        for (int a = 1; a < A; ++a) {
            float z = fmaxf(-acc[a], onePlusEps);
            if (z < bestZ) { bestZ = z; bidx = a; xy = acc[a]; }
        }
        const float d = acoshf(bestZ);

        // na into registers (one LDS read per element; <=16 distinct banks, no conflict)
        float nar[D];
#pragma unroll
        for (int j = 0; j < D; ++j) nar[j] = anch[bidx * D + j];

        float uu;
        {
            float u0 = fmaf(xy, xr[0], nar[0]);
            uu = -u0 * u0;
        }
#pragma unroll
        for (int j = 1; j < D; ++j) {
            float uj = fmaf(xy, xr[j], nar[j]);
            uu = fmaf(uj, uj, uu);
        }
        const float unorm = sqrtf(fmaxf(uu, EPS));
        const float c = ALPHA * d / unorm;
        const float vv = c * c * uu;
        const float vn = sqrtf(fmaxf(vv, EPS * EPS));
        const float sinhc = (vn > EPS) ? (sinhf(vn) / vn) : 1.0f;
        const float ch = coshf(vn);
        const float sc = sinhc * c;

        // result back into the wave's own LDS region (transpose for coalescing)
#pragma unroll
        for (int j = 0; j < D; ++j) {
            float uj = fmaf(xy, xr[j], nar[j]);
            lbase[lane * D + j] = fmaf(ch, xr[j], sc * uj);
        }
    }

    // wave-local fence: all lanes' LDS writes retired before cross-lane reads
    asm volatile("s_waitcnt lgkmcnt(0)" ::: "memory");

    // coalesced float4 store of this wave's region
    if (active && nRows == RPW) {
        float4* o4 = (float4*)(out + rowStart * D);
        const float4* l4 = (const float4*)lbase;
#pragma unroll
        for (int c = 0; c < 16; ++c) o4[c * 64 + lane] = l4[c * 64 + lane];
        out[rowStart * D + 16 * 256 + lane] = lbase[16 * 256 + lane];
    } else if (active && lane < nRows) {
        for (int j = 0; j < D; ++j)
            out[(rowStart + lane) * D + j] = lbase[lane * D + j];
    }
}

extern "C" void kernel_launch(void* const* d_in, const int* in_sizes, int n_in,
                              void* d_out, int out_size, void* d_ws, size_t ws_size,
                              hipStream_t stream) {
    const float* hyp = (const float*)d_in[0];
    const float* anchors = (const float*)d_in[1];
    float* out = (float*)d_out;
    float* ws = (float*)d_ws;

    const int B = in_sizes[0] / D;            // 1,000,000
    const int nWG = (B + RPW - 1) / RPW;      // 15,625 wave-groups
    const int grid = (nWG + WPB - 1) / WPB;   // 3,907 blocks

    prep_anchors<<<1, 256, 0, stream>>>(anchors, ws);
    homeo_kernel<<<grid, TPB, 0, stream>>>(hyp, ws, ws + A * D, out, B, nWG);
}